// Round 5
// baseline (659.225 us; speedup 1.0000x reference)
//
#include <hip/hip_runtime.h>

// Problem constants
#define NB 32
#define NS 2048
#define ND 512
#define NFF 512
#define SCALE 0.044194173824159216f

// Streaming decomposition: 64 chunks per batch, 32 rows per chunk
#define CPB 64
#define ROWS 32

__device__ __forceinline__ float dot4(float4 a, float4 b) {
    return a.x * b.x + a.y * b.y + a.z * b.z + a.w * b.w;
}

__device__ __forceinline__ float wave_reduce(float p) {
#pragma unroll
    for (int m = 1; m < 64; m <<= 1) p += __shfl_xor(p, m, 64);
    return p;
}

// ==== K_pass1: stream x -> xw (atomic); last block per batch -> kw -> wqs ====
// grid = NB*CPB = 2048 blocks, 256 threads
__global__ void __launch_bounds__(256)
k_pass1(const float* __restrict__ x, const float* __restrict__ Wt,
        const float* __restrict__ Wk, const float* __restrict__ bk,
        const float* __restrict__ Wq, const float* __restrict__ bq,
        const float* __restrict__ bt,
        float* __restrict__ xw, float* __restrict__ wqs,
        float* __restrict__ cb2, int* __restrict__ cnt1) {
    const int b = blockIdx.x >> 6;
    const int chunk = blockIdx.x & 63;
    const int t = threadIdx.x;
    const int col = t & 127;
    const int half = t >> 7;
    const float4* xb = (const float4*)(x + (size_t)b * NS * ND);

    // ---- main: chunk partial of xw ----
    {
        const int s0 = chunk * ROWS;
        float4 acc = make_float4(0.f, 0.f, 0.f, 0.f);
#pragma unroll 4
        for (int i = 0; i < 16; i++) {
            int s = s0 + half + 2 * i;
            float w = Wt[s];
            float4 v = xb[(size_t)s * 128 + col];
            acc.x += w * v.x; acc.y += w * v.y; acc.z += w * v.z; acc.w += w * v.w;
        }
        __shared__ float4 red[128];
        if (half == 1) red[col] = acc;
        __syncthreads();
        if (half == 0) {
            float4 o = red[col];
            float* dst = xw + b * ND + 4 * col;
            atomicAdd(dst + 0, acc.x + o.x);
            atomicAdd(dst + 1, acc.y + o.y);
            atomicAdd(dst + 2, acc.z + o.z);
            atomicAdd(dst + 3, acc.w + o.w);
        }
    }
    __syncthreads();

    // ---- ticket: last block of this batch proceeds ----
    __shared__ int lastFlag;
    if (t == 0) {
        int old = __hip_atomic_fetch_add(&cnt1[b], 1, __ATOMIC_ACQ_REL,
                                         __HIP_MEMORY_SCOPE_AGENT);
        lastFlag = (old == CPB - 1);
    }
    __syncthreads();
    if (!lastFlag) return;
    __threadfence();

    // ---- appendix: xw -> kw -> wqs, cb2 ----
    const int wv = t >> 6;
    const int lane = t & 63;
    __shared__ float sA[ND];
    __shared__ float kwl[NFF];
    __shared__ float cbred[4];
    __shared__ float swt_s;

    sA[t] = __hip_atomic_load(&xw[b * ND + t], __ATOMIC_RELAXED,
                              __HIP_MEMORY_SCOPE_AGENT);
    sA[256 + t] = __hip_atomic_load(&xw[b * ND + 256 + t], __ATOMIC_RELAXED,
                                    __HIP_MEMORY_SCOPE_AGENT);
    if (wv == 0) {
        float a = 0.f;
#pragma unroll
        for (int j = 0; j < 32; j++) a += Wt[j * 64 + lane];
        a = wave_reduce(a);
        if (lane == 0) swt_s = a;
    }
    __syncthreads();

    // kw: 128 f per wave
    {
        const float4* xw4 = (const float4*)sA;
        const float4 xa = xw4[lane];
        const float4 xc = xw4[64 + lane];
        const float sw = swt_s;
        float cbp = 0.f;
#pragma unroll 4
        for (int j = 0; j < 128; j++) {
            int f = wv * 128 + j;
            const float4* wr = (const float4*)(Wk + (size_t)f * ND);
            float pd = dot4(xa, wr[lane]) + dot4(xc, wr[64 + lane]);
            pd = wave_reduce(pd);
            if (lane == 0) {
                float kf = pd + bk[f] * sw;
                kwl[f] = kf;
                cbp += kf * bq[f];
            }
        }
        if (lane == 0) cbred[wv] = cbp;
    }
    __syncthreads();

    // wqs[d] = SCALE * sum_f kwl[f] * Wq[f,d]  (thread t owns d=t and d=t+256)
    {
        float a0 = 0.f, a1 = 0.f;
#pragma unroll 8
        for (int f = 0; f < NFF; f++) {
            float kf = kwl[f];
            const float* wr = Wq + (size_t)f * ND;
            a0 += kf * wr[t];
            a1 += kf * wr[256 + t];
        }
        wqs[b * ND + t] = SCALE * a0;
        wqs[b * ND + 256 + t] = SCALE * a1;
        if (t == 0)
            cb2[b] = SCALE * (cbred[0] + cbred[1] + cbred[2] + cbred[3]) + bt[0];
    }
}

// ==== K_pass2: stream x -> ta -> xt/st (atomic); last block -> out ==========
// grid = NB*CPB = 2048 blocks, 256 threads
__global__ void __launch_bounds__(256)
k_pass2(const float* __restrict__ x, const float* __restrict__ wqs,
        const float* __restrict__ cb2, const float* __restrict__ Wv,
        const float* __restrict__ bv,
        float* __restrict__ xt, float* __restrict__ st,
        float* __restrict__ out, int* __restrict__ cnt2) {
    const int b = blockIdx.x >> 6;
    const int chunk = blockIdx.x & 63;
    const int wv = threadIdx.x >> 6;
    const int lane = threadIdx.x & 63;
    const int t = threadIdx.x;
    const float4* xb = (const float4*)(x + (size_t)b * NS * ND);

    // ---- main: ta + chunk partial of xt, st ----
    {
        const float4* wq4 = (const float4*)(wqs + b * ND);
        const float4 w0 = wq4[lane];
        const float4 w1 = wq4[64 + lane];
        const float c = cb2[b];
        float4 a0 = make_float4(0.f, 0.f, 0.f, 0.f);
        float4 a1 = make_float4(0.f, 0.f, 0.f, 0.f);
        float sta = 0.f;
#pragma unroll 2
        for (int i = 0; i < 8; i++) {
            int s = chunk * ROWS + wv * 8 + i;
            float4 v0 = xb[(size_t)s * 128 + lane];
            float4 v1 = xb[(size_t)s * 128 + 64 + lane];
            float pd = dot4(v0, w0) + dot4(v1, w1);
            pd = wave_reduce(pd);
            float ta = pd + c;
            a0.x += ta * v0.x; a0.y += ta * v0.y; a0.z += ta * v0.z; a0.w += ta * v0.w;
            a1.x += ta * v1.x; a1.y += ta * v1.y; a1.z += ta * v1.z; a1.w += ta * v1.w;
            sta += ta;
        }
        __shared__ float4 sh0[4][64];
        __shared__ float4 sh1[4][64];
        __shared__ float sW[4];
        sh0[wv][lane] = a0;
        sh1[wv][lane] = a1;
        if (lane == 0) sW[wv] = sta;
        __syncthreads();
        if (t < 64) {
            float4 s0 = sh0[0][t], s1 = sh0[1][t], s2 = sh0[2][t], s3 = sh0[3][t];
            float* dst = xt + b * ND + 4 * t;
            atomicAdd(dst + 0, s0.x + s1.x + s2.x + s3.x);
            atomicAdd(dst + 1, s0.y + s1.y + s2.y + s3.y);
            atomicAdd(dst + 2, s0.z + s1.z + s2.z + s3.z);
            atomicAdd(dst + 3, s0.w + s1.w + s2.w + s3.w);
        } else if (t < 128) {
            int l = t - 64;
            float4 s0 = sh1[0][l], s1 = sh1[1][l], s2 = sh1[2][l], s3 = sh1[3][l];
            float* dst = xt + b * ND + 256 + 4 * l;
            atomicAdd(dst + 0, s0.x + s1.x + s2.x + s3.x);
            atomicAdd(dst + 1, s0.y + s1.y + s2.y + s3.y);
            atomicAdd(dst + 2, s0.z + s1.z + s2.z + s3.z);
            atomicAdd(dst + 3, s0.w + s1.w + s2.w + s3.w);
        } else if (t == 128) {
            atomicAdd(st + b, sW[0] + sW[1] + sW[2] + sW[3]);
        }
    }
    __syncthreads();

    // ---- ticket ----
    __shared__ int lastFlag;
    if (t == 0) {
        int old = __hip_atomic_fetch_add(&cnt2[b], 1, __ATOMIC_ACQ_REL,
                                         __HIP_MEMORY_SCOPE_AGENT);
        lastFlag = (old == CPB - 1);
    }
    __syncthreads();
    if (!lastFlag) return;
    __threadfence();

    // ---- appendix: out[b,f] = xt . Wv[f,:] + bv[f]*st ----
    __shared__ float sA[ND];
    __shared__ float sScalar;
    sA[t] = __hip_atomic_load(&xt[b * ND + t], __ATOMIC_RELAXED,
                              __HIP_MEMORY_SCOPE_AGENT);
    sA[256 + t] = __hip_atomic_load(&xt[b * ND + 256 + t], __ATOMIC_RELAXED,
                                    __HIP_MEMORY_SCOPE_AGENT);
    if (t == 0)
        sScalar = __hip_atomic_load(&st[b], __ATOMIC_RELAXED,
                                    __HIP_MEMORY_SCOPE_AGENT);
    __syncthreads();
    {
        const float4* xt4 = (const float4*)sA;
        const float4 xa = xt4[lane];
        const float4 xc = xt4[64 + lane];
        const float stb = sScalar;
#pragma unroll 4
        for (int j = 0; j < 128; j++) {
            int f = wv * 128 + j;
            const float4* wr = (const float4*)(Wv + (size_t)f * ND);
            float pd = dot4(xa, wr[lane]) + dot4(xc, wr[64 + lane]);
            pd = wave_reduce(pd);
            if (lane == 0) out[b * NFF + f] = pd + bv[f] * stb;
        }
    }
}

extern "C" void kernel_launch(void* const* d_in, const int* in_sizes, int n_in,
                              void* d_out, int out_size, void* d_ws, size_t ws_size,
                              hipStream_t stream) {
    const float* x  = (const float*)d_in[0];
    const float* Wq = (const float*)d_in[1];
    const float* bq = (const float*)d_in[2];
    const float* Wk = (const float*)d_in[3];
    const float* bk = (const float*)d_in[4];
    const float* Wv = (const float*)d_in[5];
    const float* bv = (const float*)d_in[6];
    const float* Wt = (const float*)d_in[7];
    const float* bt = (const float*)d_in[8];
    float* out = (float*)d_out;

    float* w = (float*)d_ws;
    float* xw   = w;                  // 16384 floats (zeroed)
    float* xt   = w + 16384;          // 16384 (zeroed)
    float* st   = w + 32768;          // 32    (zeroed)
    int*   cnt1 = (int*)(w + 32800);  // 32    (zeroed)
    int*   cnt2 = (int*)(w + 32832);  // 32    (zeroed)
    float* wqs  = w + 32864;          // 16384
    float* cb2  = w + 49248;          // 32

    // zero accumulators + counters (131,456 B)
    hipMemsetAsync(d_ws, 0, (size_t)32864 * sizeof(float), stream);

    k_pass1<<<NB * CPB, 256, 0, stream>>>(x, Wt, Wk, bk, Wq, bq, bt,
                                          xw, wqs, cb2, cnt1);
    k_pass2<<<NB * CPB, 256, 0, stream>>>(x, wqs, cb2, Wv, bv,
                                          xt, st, out, cnt2);
}

// Round 6
// 494.752 us; speedup vs baseline: 1.3324x; 1.3324x over previous
//
#include <hip/hip_runtime.h>

// Problem constants
#define NB 32
#define NS 2048
#define ND 512
#define NFF 512
#define SCALE 0.044194173824159216f

// Streaming decomposition: 64 chunks per batch, 32 rows per chunk
#define CPB 64
#define ROWS 32

__device__ __forceinline__ float dot4(float4 a, float4 b) {
    return a.x * b.x + a.y * b.y + a.z * b.z + a.w * b.w;
}

__device__ __forceinline__ float wave_reduce(float p) {
#pragma unroll
    for (int m = 1; m < 64; m <<= 1) p += __shfl_xor(p, m, 64);
    return p;
}

// Drain this wave's outstanding vmem ops (incl. atomic adds) to the
// coherence point. NO cache writeback/invalidate (the R5 killer).
__device__ __forceinline__ void drain_vmem() {
    asm volatile("s_waitcnt vmcnt(0)" ::: "memory");
}

// ==== K_pass1: stream x -> xw (atomic); last block per batch -> kw -> wqs ====
// grid = NB*CPB = 2048 blocks, 256 threads
__global__ void __launch_bounds__(256)
k_pass1(const float* __restrict__ x, const float* __restrict__ Wt,
        const float* __restrict__ Wk, const float* __restrict__ bk,
        const float* __restrict__ Wq, const float* __restrict__ bq,
        const float* __restrict__ bt,
        float* __restrict__ xw, float* __restrict__ wqs,
        float* __restrict__ cb2, int* __restrict__ cnt1) {
    const int b = blockIdx.x >> 6;
    const int chunk = blockIdx.x & 63;
    const int t = threadIdx.x;
    const int col = t & 127;
    const int half = t >> 7;
    const float4* xb = (const float4*)(x + (size_t)b * NS * ND);

    // ---- main: chunk partial of xw ----
    {
        const int s0 = chunk * ROWS;
        float4 acc = make_float4(0.f, 0.f, 0.f, 0.f);
#pragma unroll 4
        for (int i = 0; i < 16; i++) {
            int s = s0 + half + 2 * i;
            float w = Wt[s];
            float4 v = xb[(size_t)s * 128 + col];
            acc.x += w * v.x; acc.y += w * v.y; acc.z += w * v.z; acc.w += w * v.w;
        }
        __shared__ float4 red[128];
        if (half == 1) red[col] = acc;
        __syncthreads();
        if (half == 0) {
            float4 o = red[col];
            float* dst = xw + b * ND + 4 * col;
            atomicAdd(dst + 0, acc.x + o.x);
            atomicAdd(dst + 1, acc.y + o.y);
            atomicAdd(dst + 2, acc.z + o.z);
            atomicAdd(dst + 3, acc.w + o.w);
        }
    }
    // every lane drains its own vmem before the block tickets
    drain_vmem();
    __syncthreads();

    // ---- ticket (RELAXED - no cache maintenance) ----
    __shared__ int lastFlag;
    if (t == 0) {
        int old = __hip_atomic_fetch_add(&cnt1[b], 1, __ATOMIC_RELAXED,
                                         __HIP_MEMORY_SCOPE_AGENT);
        lastFlag = (old == CPB - 1);
    }
    __syncthreads();
    if (!lastFlag) return;

    // ---- appendix: xw -> kw -> wqs, cb2 ----
    const int wv = t >> 6;
    const int lane = t & 63;
    __shared__ float sA[ND];
    __shared__ float kwl[NFF];
    __shared__ float cbred[4];
    __shared__ float swt_s;

    sA[t] = __hip_atomic_load(&xw[b * ND + t], __ATOMIC_RELAXED,
                              __HIP_MEMORY_SCOPE_AGENT);
    sA[256 + t] = __hip_atomic_load(&xw[b * ND + 256 + t], __ATOMIC_RELAXED,
                                    __HIP_MEMORY_SCOPE_AGENT);
    if (wv == 0) {
        float a = 0.f;
#pragma unroll
        for (int j = 0; j < 32; j++) a += Wt[j * 64 + lane];
        a = wave_reduce(a);
        if (lane == 0) swt_s = a;
    }
    __syncthreads();

    // kw: 128 f per wave
    {
        const float4* xw4 = (const float4*)sA;
        const float4 xa = xw4[lane];
        const float4 xc = xw4[64 + lane];
        const float sw = swt_s;
        float cbp = 0.f;
#pragma unroll 4
        for (int j = 0; j < 128; j++) {
            int f = wv * 128 + j;
            const float4* wr = (const float4*)(Wk + (size_t)f * ND);
            float pd = dot4(xa, wr[lane]) + dot4(xc, wr[64 + lane]);
            pd = wave_reduce(pd);
            if (lane == 0) {
                float kf = pd + bk[f] * sw;
                kwl[f] = kf;
                cbp += kf * bq[f];
            }
        }
        if (lane == 0) cbred[wv] = cbp;
    }
    __syncthreads();

    // wqs[d] = SCALE * sum_f kwl[f] * Wq[f,d]  (thread t owns d=t and d=t+256)
    {
        float a0 = 0.f, a1 = 0.f;
#pragma unroll 8
        for (int f = 0; f < NFF; f++) {
            float kf = kwl[f];
            const float* wr = Wq + (size_t)f * ND;
            a0 += kf * wr[t];
            a1 += kf * wr[256 + t];
        }
        wqs[b * ND + t] = SCALE * a0;
        wqs[b * ND + 256 + t] = SCALE * a1;
        if (t == 0)
            cb2[b] = SCALE * (cbred[0] + cbred[1] + cbred[2] + cbred[3]) + bt[0];
    }
}

// ==== K_pass2: stream x -> ta -> xt/st (atomic); last block -> out ==========
// grid = NB*CPB = 2048 blocks, 256 threads
__global__ void __launch_bounds__(256)
k_pass2(const float* __restrict__ x, const float* __restrict__ wqs,
        const float* __restrict__ cb2, const float* __restrict__ Wv,
        const float* __restrict__ bv,
        float* __restrict__ xt, float* __restrict__ st,
        float* __restrict__ out, int* __restrict__ cnt2) {
    const int b = blockIdx.x >> 6;
    const int chunk = blockIdx.x & 63;
    const int wv = threadIdx.x >> 6;
    const int lane = threadIdx.x & 63;
    const int t = threadIdx.x;
    const float4* xb = (const float4*)(x + (size_t)b * NS * ND);

    // ---- main: ta + chunk partial of xt, st ----
    {
        const float4* wq4 = (const float4*)(wqs + b * ND);
        const float4 w0 = wq4[lane];
        const float4 w1 = wq4[64 + lane];
        const float c = cb2[b];
        float4 a0 = make_float4(0.f, 0.f, 0.f, 0.f);
        float4 a1 = make_float4(0.f, 0.f, 0.f, 0.f);
        float sta = 0.f;
#pragma unroll 2
        for (int i = 0; i < 8; i++) {
            int s = chunk * ROWS + wv * 8 + i;
            float4 v0 = xb[(size_t)s * 128 + lane];
            float4 v1 = xb[(size_t)s * 128 + 64 + lane];
            float pd = dot4(v0, w0) + dot4(v1, w1);
            pd = wave_reduce(pd);
            float ta = pd + c;
            a0.x += ta * v0.x; a0.y += ta * v0.y; a0.z += ta * v0.z; a0.w += ta * v0.w;
            a1.x += ta * v1.x; a1.y += ta * v1.y; a1.z += ta * v1.z; a1.w += ta * v1.w;
            sta += ta;
        }
        __shared__ float4 sh0[4][64];
        __shared__ float4 sh1[4][64];
        __shared__ float sW[4];
        sh0[wv][lane] = a0;
        sh1[wv][lane] = a1;
        if (lane == 0) sW[wv] = sta;
        __syncthreads();
        if (t < 64) {
            float4 s0 = sh0[0][t], s1 = sh0[1][t], s2 = sh0[2][t], s3 = sh0[3][t];
            float* dst = xt + b * ND + 4 * t;
            atomicAdd(dst + 0, s0.x + s1.x + s2.x + s3.x);
            atomicAdd(dst + 1, s0.y + s1.y + s2.y + s3.y);
            atomicAdd(dst + 2, s0.z + s1.z + s2.z + s3.z);
            atomicAdd(dst + 3, s0.w + s1.w + s2.w + s3.w);
        } else if (t < 128) {
            int l = t - 64;
            float4 s0 = sh1[0][l], s1 = sh1[1][l], s2 = sh1[2][l], s3 = sh1[3][l];
            float* dst = xt + b * ND + 256 + 4 * l;
            atomicAdd(dst + 0, s0.x + s1.x + s2.x + s3.x);
            atomicAdd(dst + 1, s0.y + s1.y + s2.y + s3.y);
            atomicAdd(dst + 2, s0.z + s1.z + s2.z + s3.z);
            atomicAdd(dst + 3, s0.w + s1.w + s2.w + s3.w);
        } else if (t == 128) {
            atomicAdd(st + b, sW[0] + sW[1] + sW[2] + sW[3]);
        }
    }
    drain_vmem();
    __syncthreads();

    // ---- ticket (RELAXED) ----
    __shared__ int lastFlag;
    if (t == 0) {
        int old = __hip_atomic_fetch_add(&cnt2[b], 1, __ATOMIC_RELAXED,
                                         __HIP_MEMORY_SCOPE_AGENT);
        lastFlag = (old == CPB - 1);
    }
    __syncthreads();
    if (!lastFlag) return;

    // ---- appendix: out[b,f] = xt . Wv[f,:] + bv[f]*st ----
    __shared__ float sA[ND];
    __shared__ float sScalar;
    sA[t] = __hip_atomic_load(&xt[b * ND + t], __ATOMIC_RELAXED,
                              __HIP_MEMORY_SCOPE_AGENT);
    sA[256 + t] = __hip_atomic_load(&xt[b * ND + 256 + t], __ATOMIC_RELAXED,
                                    __HIP_MEMORY_SCOPE_AGENT);
    if (t == 0)
        sScalar = __hip_atomic_load(&st[b], __ATOMIC_RELAXED,
                                    __HIP_MEMORY_SCOPE_AGENT);
    __syncthreads();
    {
        const float4* xt4 = (const float4*)sA;
        const float4 xa = xt4[lane];
        const float4 xc = xt4[64 + lane];
        const float stb = sScalar;
#pragma unroll 4
        for (int j = 0; j < 128; j++) {
            int f = wv * 128 + j;
            const float4* wr = (const float4*)(Wv + (size_t)f * ND);
            float pd = dot4(xa, wr[lane]) + dot4(xc, wr[64 + lane]);
            pd = wave_reduce(pd);
            if (lane == 0) out[b * NFF + f] = pd + bv[f] * stb;
        }
    }
}

extern "C" void kernel_launch(void* const* d_in, const int* in_sizes, int n_in,
                              void* d_out, int out_size, void* d_ws, size_t ws_size,
                              hipStream_t stream) {
    const float* x  = (const float*)d_in[0];
    const float* Wq = (const float*)d_in[1];
    const float* bq = (const float*)d_in[2];
    const float* Wk = (const float*)d_in[3];
    const float* bk = (const float*)d_in[4];
    const float* Wv = (const float*)d_in[5];
    const float* bv = (const float*)d_in[6];
    const float* Wt = (const float*)d_in[7];
    const float* bt = (const float*)d_in[8];
    float* out = (float*)d_out;

    float* w = (float*)d_ws;
    float* xw   = w;                  // 16384 floats (zeroed)
    float* xt   = w + 16384;          // 16384 (zeroed)
    float* st   = w + 32768;          // 32    (zeroed)
    int*   cnt1 = (int*)(w + 32800);  // 32    (zeroed)
    int*   cnt2 = (int*)(w + 32832);  // 32    (zeroed)
    float* wqs  = w + 32864;          // 16384
    float* cb2  = w + 49248;          // 32

    // zero accumulators + counters (131,456 B)
    hipMemsetAsync(d_ws, 0, (size_t)32864 * sizeof(float), stream);

    k_pass1<<<NB * CPB, 256, 0, stream>>>(x, Wt, Wk, bk, Wq, bq, bt,
                                          xw, wqs, cb2, cnt1);
    k_pass2<<<NB * CPB, 256, 0, stream>>>(x, wqs, cb2, Wv, bv,
                                          xt, st, out, cnt2);
}

// Round 7
// 268.140 us; speedup vs baseline: 2.4585x; 1.8451x over previous
//
#include <hip/hip_runtime.h>

// Problem constants
#define NB 32
#define NS 2048
#define ND 512
#define NFF 512
#define SCALE 0.044194173824159216f

// Streaming decomposition: 64 chunks per batch, 32 rows per chunk
#define CPB 64
#define ROWS 32

__device__ __forceinline__ float dot4(float4 a, float4 b) {
    return a.x * b.x + a.y * b.y + a.z * b.z + a.w * b.w;
}

__device__ __forceinline__ float wave_reduce(float p) {
#pragma unroll
    for (int m = 1; m < 64; m <<= 1) p += __shfl_xor(p, m, 64);
    return p;
}

// ---- K1: xwp[blk][d] = sum_{s in chunk} Wt[s]*x[b,s,d]  (pass 1) -----------
// grid = NB*64 = 2048 blocks, 256 threads. Blocks 0..31 also zero the
// wqs/cb2 accumulators for batch bz=blockIdx (k_kw runs strictly after, so
// no race and no extra memset launch).
__global__ void __launch_bounds__(256) k_xw(const float* __restrict__ x,
                                            const float* __restrict__ Wt,
                                            float* __restrict__ xwp,
                                            float* __restrict__ wqs,
                                            float* __restrict__ cb2) {
    const int b = blockIdx.x >> 6;
    const int chunk = blockIdx.x & 63;
    const int s0 = chunk * ROWS;
    const int t = threadIdx.x;
    const int col = t & 127;   // float4 column
    const int half = t >> 7;   // row interleave (0/1)

    if (blockIdx.x < NB) {     // zero accumulators for batch bz = blockIdx.x
        const int bz = blockIdx.x;
        wqs[bz * ND + t] = 0.f;
        wqs[bz * ND + 256 + t] = 0.f;
        if (t == 0) cb2[bz] = 0.f;
    }

    const float4* xb = (const float4*)(x + (size_t)b * NS * ND);
    float4 acc = make_float4(0.f, 0.f, 0.f, 0.f);
#pragma unroll 4
    for (int i = 0; i < 16; i++) {
        int s = s0 + half + 2 * i;
        float w = Wt[s];
        float4 v = xb[(size_t)s * 128 + col];
        acc.x += w * v.x; acc.y += w * v.y; acc.z += w * v.z; acc.w += w * v.w;
    }
    __shared__ float4 red[128];
    if (half == 1) red[col] = acc;
    __syncthreads();
    if (half == 0) {
        float4 o = red[col];
        o.x += acc.x; o.y += acc.y; o.z += acc.z; o.w += acc.w;
        ((float4*)xwp)[(size_t)blockIdx.x * 128 + col] = o;
    }
}

// ---- K2': per block (b, 64 f's): kw_scaled -> wqs partial (atomic), cb2 ----
// grid = 256 blocks (8 per b, 64 f each), 256 threads
__global__ void __launch_bounds__(256) k_kw(const float* __restrict__ xwp,
                                            const float* __restrict__ Wt,
                                            const float* __restrict__ Wk,
                                            const float* __restrict__ bk,
                                            const float* __restrict__ Wq,
                                            const float* __restrict__ bq,
                                            const float* __restrict__ bt,
                                            float* __restrict__ wqs,
                                            float* __restrict__ cb2) {
    const int b = blockIdx.x >> 3;
    const int f0 = (blockIdx.x & 7) * 64;
    const int t = threadIdx.x;
    const int wv = t >> 6;
    const int lane = t & 63;
    __shared__ float sA[ND];
    __shared__ float kfl[64];   // SCALE * kw for this block's 64 f's
    __shared__ float sW[4];
    __shared__ float swt_s;
    // Stage A: reduce the 64 xwp partial rows of batch b
    {
        float a0 = 0.f, a1 = 0.f;
        const float* p = xwp + (size_t)b * CPB * ND + t;
#pragma unroll 8
        for (int c = 0; c < CPB; c++) {
            a0 += p[(size_t)c * ND];
            a1 += p[(size_t)c * ND + 256];
        }
        sA[t] = a0;
        sA[256 + t] = a1;
    }
    if (wv == 0) {
        float a = 0.f;
#pragma unroll
        for (int j = 0; j < 32; j++) a += Wt[j * 64 + lane];
        a = wave_reduce(a);
        if (lane == 0) swt_s = a;
    }
    __syncthreads();
    // Stage B: 16 f's per wave -> kfl (scaled); cb2 partial per wave
    {
        const float4* xw4 = (const float4*)sA;
        const float4 xa = xw4[lane];
        const float4 xc = xw4[64 + lane];
        const float sw = swt_s;
        float cbp = 0.f;
#pragma unroll 4
        for (int j = 0; j < 16; j++) {
            int f = f0 + wv * 16 + j;
            const float4* wr = (const float4*)(Wk + (size_t)f * ND);
            float pd = dot4(xa, wr[lane]) + dot4(xc, wr[64 + lane]);
            pd = wave_reduce(pd);
            if (lane == 0) {
                float kfs = SCALE * (pd + bk[f] * sw);
                kfl[wv * 16 + j] = kfs;
                cbp += kfs * bq[f];
            }
        }
        if (lane == 0) sW[wv] = cbp;
    }
    __syncthreads();
    // Stage C: wqs[b,d] += sum_{j<64} kfl[j]*Wq[f0+j,d]  (atomic partials)
    {
        float a0 = 0.f, a1 = 0.f;
#pragma unroll 8
        for (int j = 0; j < 64; j++) {
            float kf = kfl[j];
            const float* wr = Wq + (size_t)(f0 + j) * ND;
            a0 += kf * wr[t];
            a1 += kf * wr[256 + t];
        }
        atomicAdd(&wqs[b * ND + t], a0);
        atomicAdd(&wqs[b * ND + 256 + t], a1);
        if (t == 0) {
            float c = sW[0] + sW[1] + sW[2] + sW[3];
            if ((blockIdx.x & 7) == 0) c += bt[0];
            atomicAdd(&cb2[b], c);
        }
    }
}

// ---- K3: ta = x.wqs + cb2; xtp[blk][d] = sum_s ta*x; stp[blk] (pass 2, L3) -
// grid = 2048 blocks (32 rows), 256 threads = 4 waves, 8 rows/wave
__global__ void __launch_bounds__(256) k_ta_xt(const float* __restrict__ x,
                                               const float* __restrict__ wqs,
                                               const float* __restrict__ cb2,
                                               float* __restrict__ xtp,
                                               float* __restrict__ stp) {
    const int b = blockIdx.x >> 6;
    const int chunk = blockIdx.x & 63;
    const int wv = threadIdx.x >> 6;
    const int lane = threadIdx.x & 63;
    const float4* xb = (const float4*)(x + (size_t)b * NS * ND);
    const float4* wq4 = (const float4*)(wqs + b * ND);
    const float4 w0 = wq4[lane];
    const float4 w1 = wq4[64 + lane];
    const float c = cb2[b];
    float4 a0 = make_float4(0.f, 0.f, 0.f, 0.f);
    float4 a1 = make_float4(0.f, 0.f, 0.f, 0.f);
    float sta = 0.f;
#pragma unroll 2
    for (int i = 0; i < 8; i++) {
        int s = chunk * ROWS + wv * 8 + i;
        float4 v0 = xb[(size_t)s * 128 + lane];
        float4 v1 = xb[(size_t)s * 128 + 64 + lane];
        float pd = dot4(v0, w0) + dot4(v1, w1);
        pd = wave_reduce(pd);
        float ta = pd + c;
        a0.x += ta * v0.x; a0.y += ta * v0.y; a0.z += ta * v0.z; a0.w += ta * v0.w;
        a1.x += ta * v1.x; a1.y += ta * v1.y; a1.z += ta * v1.z; a1.w += ta * v1.w;
        sta += ta;
    }
    __shared__ float4 sh0[4][64];
    __shared__ float4 sh1[4][64];
    __shared__ float sW[4];
    sh0[wv][lane] = a0;
    sh1[wv][lane] = a1;
    if (lane == 0) sW[wv] = sta;
    __syncthreads();
    const int t = threadIdx.x;
    float4* dst = (float4*)xtp + (size_t)blockIdx.x * 128;
    if (t < 64) {
        float4 s0 = sh0[0][t], s1 = sh0[1][t], s2 = sh0[2][t], s3 = sh0[3][t];
        dst[t] = make_float4(s0.x + s1.x + s2.x + s3.x,
                             s0.y + s1.y + s2.y + s3.y,
                             s0.z + s1.z + s2.z + s3.z,
                             s0.w + s1.w + s2.w + s3.w);
    } else if (t < 128) {
        int l = t - 64;
        float4 s0 = sh1[0][l], s1 = sh1[1][l], s2 = sh1[2][l], s3 = sh1[3][l];
        dst[64 + l] = make_float4(s0.x + s1.x + s2.x + s3.x,
                                  s0.y + s1.y + s2.y + s3.y,
                                  s0.z + s1.z + s2.z + s3.z,
                                  s0.w + s1.w + s2.w + s3.w);
    } else if (t == 128) {
        stp[blockIdx.x] = sW[0] + sW[1] + sW[2] + sW[3];
    }
}

// ---- K4: out[b,f] = xt.Wv[f,:] + bv[f]*st, reducing xtp/stp ----------------
// grid = 256 blocks (8 per b, 64 f each), 256 threads
__global__ void __launch_bounds__(256) k_latent(const float* __restrict__ xtp,
                                                const float* __restrict__ stp,
                                                const float* __restrict__ Wv,
                                                const float* __restrict__ bv,
                                                float* __restrict__ out) {
    const int b = blockIdx.x >> 3;
    const int f0 = (blockIdx.x & 7) * 64;
    const int t = threadIdx.x;
    const int wv = t >> 6;
    const int lane = t & 63;
    __shared__ float sA[ND];
    __shared__ float sts;
    {
        float a0 = 0.f, a1 = 0.f;
        const float* p = xtp + (size_t)b * CPB * ND + t;
#pragma unroll 8
        for (int c = 0; c < CPB; c++) {
            a0 += p[(size_t)c * ND];
            a1 += p[(size_t)c * ND + 256];
        }
        sA[t] = a0;
        sA[256 + t] = a1;
        if (t == 0) {
            float s = 0.f;
            const float* sp = stp + b * CPB;
#pragma unroll
            for (int c = 0; c < CPB; c++) s += sp[c];
            sts = s;
        }
    }
    __syncthreads();
    const float4* xt4 = (const float4*)sA;
    const float4 xa = xt4[lane];
    const float4 xc = xt4[64 + lane];
    const float stb = sts;
#pragma unroll 4
    for (int j = 0; j < 16; j++) {
        int f = f0 + wv * 16 + j;
        const float4* wr = (const float4*)(Wv + (size_t)f * ND);
        float pd = dot4(xa, wr[lane]) + dot4(xc, wr[64 + lane]);
        pd = wave_reduce(pd);
        if (lane == 0) out[b * NFF + f] = pd + bv[f] * stb;
    }
}

extern "C" void kernel_launch(void* const* d_in, const int* in_sizes, int n_in,
                              void* d_out, int out_size, void* d_ws, size_t ws_size,
                              hipStream_t stream) {
    const float* x  = (const float*)d_in[0];
    const float* Wq = (const float*)d_in[1];
    const float* bq = (const float*)d_in[2];
    const float* Wk = (const float*)d_in[3];
    const float* bk = (const float*)d_in[4];
    const float* Wv = (const float*)d_in[5];
    const float* bv = (const float*)d_in[6];
    const float* Wt = (const float*)d_in[7];
    const float* bt = (const float*)d_in[8];
    float* out = (float*)d_out;

    float* w = (float*)d_ws;
    float* xwp  = w;                 // 2048*512 = 1048576
    float* xtp  = w + 1048576;       // 1048576
    float* stp  = w + 2097152;       // 2048
    float* wqs  = w + 2099200;       // 16384 (zeroed by k_xw blocks 0..31)
    float* cb2  = w + 2115584;       // 32    (zeroed by k_xw)

    k_xw<<<NB * CPB, 256, 0, stream>>>(x, Wt, xwp, wqs, cb2);
    k_kw<<<256, 256, 0, stream>>>(xwp, Wt, Wk, bk, Wq, bq, bt, wqs, cb2);
    k_ta_xt<<<NB * CPB, 256, 0, stream>>>(x, wqs, cb2, xtp, stp);
    k_latent<<<256, 256, 0, stream>>>(xtp, stp, Wv, bv, out);
}